// Round 1
// baseline (388.488 us; speedup 1.0000x reference)
//
#include <hip/hip_runtime.h>
#include <cstdint>
#include <cstddef>

typedef __bf16 bf16;
typedef __attribute__((ext_vector_type(8))) __bf16 bf16x8;
typedef __attribute__((ext_vector_type(4))) __bf16 bf16x4;
typedef __attribute__((ext_vector_type(4))) float f32x4;

#define MFMA16 __builtin_amdgcn_mfma_f32_16x16x32_bf16

// ---------------------------------------------------------------------------
// Tiled transpose + fp32->bf16 cast:  src [K][N] fp32  ->  dst [N][K] bf16
// ---------------------------------------------------------------------------
__global__ __launch_bounds__(256) void transpose_cast(
    const float* __restrict__ src, bf16* __restrict__ dst, int K, int N)
{
    __shared__ float t[32][33];
    const int n0 = blockIdx.x * 32, k0 = blockIdx.y * 32;
    const int tx = threadIdx.x, ty = threadIdx.y;
    #pragma unroll
    for (int i = ty; i < 32; i += 8)
        t[i][tx] = src[(size_t)(k0 + i) * N + n0 + tx];
    __syncthreads();
    #pragma unroll
    for (int i = ty; i < 32; i += 8)
        dst[(size_t)(n0 + i) * K + k0 + tx] = (bf16)t[tx][i];
}

// ---------------------------------------------------------------------------
// Batched bf16 transpose for V: src [Z][2048][64] -> dst [Z][64][2048]
// ---------------------------------------------------------------------------
__global__ __launch_bounds__(256) void transpose_v(
    const bf16* __restrict__ src, bf16* __restrict__ dst)
{
    __shared__ bf16 t[32][33];
    const int z = blockIdx.z;
    const int h0 = blockIdx.x * 32, s0 = blockIdx.y * 32;
    const bf16* sp = src + (size_t)z * 2048 * 64;
    bf16* dp = dst + (size_t)z * 64 * 2048;
    const int tx = threadIdx.x, ty = threadIdx.y;
    #pragma unroll
    for (int i = ty; i < 32; i += 8)
        t[i][tx] = sp[(size_t)(s0 + i) * 64 + h0 + tx];
    __syncthreads();
    #pragma unroll
    for (int i = ty; i < 32; i += 8)
        dp[(size_t)(h0 + i) * 2048 + s0 + tx] = t[tx][i];
}

// ---------------------------------------------------------------------------
// LayerNorm (D=1024) fp32 in -> bf16 out. One block (256 thr) per row.
// ---------------------------------------------------------------------------
__global__ __launch_bounds__(256) void ln_kernel(
    const float* __restrict__ x, const float* __restrict__ sc,
    const float* __restrict__ bi, bf16* __restrict__ y)
{
    const int row = blockIdx.x, tid = threadIdx.x;
    const f32x4 v = ((const f32x4*)(x + (size_t)row * 1024))[tid];
    float s  = v[0] + v[1] + v[2] + v[3];
    float s2 = v[0]*v[0] + v[1]*v[1] + v[2]*v[2] + v[3]*v[3];
    #pragma unroll
    for (int d = 1; d < 64; d <<= 1) {
        s  += __shfl_xor(s, d);
        s2 += __shfl_xor(s2, d);
    }
    __shared__ float red[8];
    if ((tid & 63) == 0) { red[tid >> 6] = s; red[4 + (tid >> 6)] = s2; }
    __syncthreads();
    s  = red[0] + red[1] + red[2] + red[3];
    s2 = red[4] + red[5] + red[6] + red[7];
    const float mu = s * (1.f / 1024.f);
    const float rstd = rsqrtf(s2 * (1.f / 1024.f) - mu * mu + 1e-6f);
    const f32x4 s4 = ((const f32x4*)sc)[tid];
    const f32x4 b4 = ((const f32x4*)bi)[tid];
    bf16x4 o;
    #pragma unroll
    for (int j = 0; j < 4; ++j)
        o[j] = (bf16)((v[j] - mu) * rstd * s4[j] + b4[j]);
    ((bf16x4*)(y + (size_t)row * 1024))[tid] = o;
}

// ---------------------------------------------------------------------------
// bf16 GEMM: C[M][N] = A[M][K] @ Bt[N][K]^T  (Bt pre-transposed, row-major)
// 128x128 tile, BK=32, 256 threads = 4 waves (2x2), 4x4 16x16x32 frags/wave.
// EPI 0: QKV scatter  (+bias, bf16 out to [B][N][T][H] x3)
// EPI 1: fp32 out = acc + bias[col] + res[row][col]
// EPI 2: bf16 out = gelu_tanh(acc + bias[col])
// ---------------------------------------------------------------------------
template <int EPI>
__global__ __launch_bounds__(256) void gemm_kernel(
    const bf16* __restrict__ A, const bf16* __restrict__ Bt,
    int M, int N, int K,
    const float* __restrict__ b0, const float* __restrict__ b1,
    const float* __restrict__ b2, const float* __restrict__ res,
    bf16* __restrict__ o0, bf16* __restrict__ o1, bf16* __restrict__ o2,
    float* __restrict__ of)
{
    __shared__ bf16 As[128][40];  // +8 pad: conflict-free b128 reads
    __shared__ bf16 Bs[128][40];

    const int tid = threadIdx.x;
    const int wave = tid >> 6, lane = tid & 63;
    const int wr = (wave >> 1) * 64, wc = (wave & 1) * 64;
    const int lr = lane & 15, lk = (lane >> 4) * 8;
    const int bm = blockIdx.y * 128, bn = blockIdx.x * 128;

    f32x4 acc[4][4] = {};

    const int r0 = tid >> 2, oc = (tid & 3) * 8;
    const bf16* Ap = A + (size_t)(bm + r0) * K + oc;
    const bf16* Bp = Bt + (size_t)(bn + r0) * K + oc;

    for (int k0 = 0; k0 < K; k0 += 32) {
        *(bf16x8*)&As[r0][oc]      = *(const bf16x8*)(Ap + k0);
        *(bf16x8*)&As[r0 + 64][oc] = *(const bf16x8*)(Ap + (size_t)64 * K + k0);
        *(bf16x8*)&Bs[r0][oc]      = *(const bf16x8*)(Bp + k0);
        *(bf16x8*)&Bs[r0 + 64][oc] = *(const bf16x8*)(Bp + (size_t)64 * K + k0);
        __syncthreads();
        bf16x8 a[4], b[4];
        #pragma unroll
        for (int m = 0; m < 4; ++m) a[m] = *(const bf16x8*)&As[wr + m * 16 + lr][lk];
        #pragma unroll
        for (int n = 0; n < 4; ++n) b[n] = *(const bf16x8*)&Bs[wc + n * 16 + lr][lk];
        #pragma unroll
        for (int m = 0; m < 4; ++m)
            #pragma unroll
            for (int n = 0; n < 4; ++n)
                acc[m][n] = MFMA16(a[m], b[n], acc[m][n], 0, 0, 0);
        __syncthreads();
    }

    const int rbase = bm + wr + ((lane >> 4) << 2);
    const int cbase = bn + wc + lr;
    #pragma unroll
    for (int m = 0; m < 4; ++m) {
        #pragma unroll
        for (int n = 0; n < 4; ++n) {
            const f32x4 v = acc[m][n];
            #pragma unroll
            for (int r = 0; r < 4; ++r) {
                const int row = rbase + m * 16 + r;
                const int col = cbase + n * 16;
                const float val = v[r];
                if constexpr (EPI == 0) {
                    const int which = col >> 10, cc = col & 1023;
                    const float* bp = (which == 0) ? b0 : (which == 1) ? b1 : b2;
                    bf16* dp = (which == 0) ? o0 : (which == 1) ? o1 : o2;
                    const int bb = row >> 11, t = row & 2047;
                    const int nh = cc >> 6, hh = cc & 63;
                    dp[(((size_t)(bb * 16 + nh) * 2048 + t) << 6) + hh] =
                        (bf16)(val + bp[cc]);
                } else if constexpr (EPI == 1) {
                    of[(size_t)row * N + col] =
                        val + b0[col] + res[(size_t)row * N + col];
                } else {
                    const float xg = val + b0[col];
                    const float g = 0.5f * xg *
                        (1.f + tanhf(0.7978845608f * (xg + 0.044715f * xg * xg * xg)));
                    o0[(size_t)row * N + col] = (bf16)g;
                }
            }
        }
    }
}

// ---------------------------------------------------------------------------
// Flash attention. Grid: (qt=T/64, z=B*N). 256 thr = 4 waves; each wave owns
// 16 Q rows. K tile [64 s][64 h], Vt tile [64 h][64 s] staged in LDS.
// Online softmax wave-parallel via 16-lane shfl_xor groups.
// q,k: [Z][T][H] bf16; vt: [Z][H][T] bf16; enc out: [B][T][N*H] bf16.
// ---------------------------------------------------------------------------
__global__ __launch_bounds__(256) void attn_kernel(
    const bf16* __restrict__ q, const bf16* __restrict__ k,
    const bf16* __restrict__ vt, bf16* __restrict__ enc)
{
    __shared__ bf16 Qs[64][72];
    __shared__ bf16 Ks[64][72];
    __shared__ bf16 Vs[64][72];       // [h][s]
    __shared__ bf16 Ps[4][16][72];    // per-wave P tile

    const int tid = threadIdx.x, wave = tid >> 6, lane = tid & 63;
    const int lr = lane & 15, lk = (lane >> 4) * 8;
    const int qt = blockIdx.x, z = blockIdx.y;
    const bf16* qb = q + ((size_t)z * 2048 + qt * 64) * 64;
    const bf16* kb = k + (size_t)z * 2048 * 64;
    const bf16* vb = vt + (size_t)z * 64 * 2048;

    for (int c = tid; c < 512; c += 256) {
        const int r = c >> 3, o = (c & 7) * 8;
        *(bf16x8*)&Qs[r][o] = *(const bf16x8*)&qb[r * 64 + o];
    }
    __syncthreads();
    bf16x8 aq0 = *(const bf16x8*)&Qs[wave * 16 + lr][lk];
    bf16x8 aq1 = *(const bf16x8*)&Qs[wave * 16 + lr][32 + lk];

    float m_run[4] = {-1e30f, -1e30f, -1e30f, -1e30f};
    float l_run[4] = {0.f, 0.f, 0.f, 0.f};
    f32x4 accO[4] = {};

    for (int st = 0; st < 32; ++st) {
        __syncthreads();
        for (int c = tid; c < 512; c += 256) {
            const int r = c >> 3, o = (c & 7) * 8;
            *(bf16x8*)&Ks[r][o] = *(const bf16x8*)&kb[(size_t)(st * 64 + r) * 64 + o];
            *(bf16x8*)&Vs[r][o] = *(const bf16x8*)&vb[(size_t)r * 2048 + st * 64 + o];
        }
        __syncthreads();

        f32x4 sa[4] = {};
        #pragma unroll
        for (int j = 0; j < 4; ++j) {
            sa[j] = MFMA16(aq0, *(const bf16x8*)&Ks[j * 16 + lr][lk], sa[j], 0, 0, 0);
            sa[j] = MFMA16(aq1, *(const bf16x8*)&Ks[j * 16 + lr][32 + lk], sa[j], 0, 0, 0);
        }
        #pragma unroll
        for (int j = 0; j < 4; ++j)
            #pragma unroll
            for (int r = 0; r < 4; ++r) sa[j][r] *= 0.125f;  // H^-0.5

        float pm[4];
        #pragma unroll
        for (int r = 0; r < 4; ++r)
            pm[r] = fmaxf(fmaxf(sa[0][r], sa[1][r]), fmaxf(sa[2][r], sa[3][r]));
        #pragma unroll
        for (int d = 1; d < 16; d <<= 1)
            #pragma unroll
            for (int r = 0; r < 4; ++r) pm[r] = fmaxf(pm[r], __shfl_xor(pm[r], d));

        float fac[4], rs[4];
        #pragma unroll
        for (int r = 0; r < 4; ++r) {
            const float mn = fmaxf(m_run[r], pm[r]);
            fac[r] = __expf(m_run[r] - mn);
            m_run[r] = mn;
            rs[r] = 0.f;
        }
        #pragma unroll
        for (int j = 0; j < 4; ++j)
            #pragma unroll
            for (int r = 0; r < 4; ++r) {
                const float p = __expf(sa[j][r] - m_run[r]);
                sa[j][r] = p;
                rs[r] += p;
            }
        #pragma unroll
        for (int d = 1; d < 16; d <<= 1)
            #pragma unroll
            for (int r = 0; r < 4; ++r) rs[r] += __shfl_xor(rs[r], d);
        #pragma unroll
        for (int r = 0; r < 4; ++r) l_run[r] = l_run[r] * fac[r] + rs[r];

        #pragma unroll
        for (int nh = 0; nh < 4; ++nh)
            #pragma unroll
            for (int r = 0; r < 4; ++r) accO[nh][r] *= fac[r];

        #pragma unroll
        for (int j = 0; j < 4; ++j)
            #pragma unroll
            for (int r = 0; r < 4; ++r)
                Ps[wave][((lane >> 4) << 2) + r][j * 16 + lr] = (bf16)sa[j][r];

        #pragma unroll
        for (int nh = 0; nh < 4; ++nh) {
            accO[nh] = MFMA16(*(const bf16x8*)&Ps[wave][lr][lk],
                              *(const bf16x8*)&Vs[nh * 16 + lr][lk], accO[nh], 0, 0, 0);
            accO[nh] = MFMA16(*(const bf16x8*)&Ps[wave][lr][32 + lk],
                              *(const bf16x8*)&Vs[nh * 16 + lr][32 + lk], accO[nh], 0, 0, 0);
        }
    }

    const int bb = z >> 4, nn = z & 15;
    #pragma unroll
    for (int nh = 0; nh < 4; ++nh)
        #pragma unroll
        for (int r = 0; r < 4; ++r) {
            const int t = qt * 64 + wave * 16 + ((lane >> 4) << 2) + r;
            const int hh = nh * 16 + lr;
            enc[((size_t)(bb * 2048 + t)) * 1024 + nn * 64 + hh] =
                (bf16)(accO[nh][r] / l_run[r]);
        }
}

// ---------------------------------------------------------------------------
extern "C" void kernel_launch(void* const* d_in, const int* in_sizes, int n_in,
                              void* d_out, int out_size, void* d_ws, size_t ws_size,
                              hipStream_t stream) {
    const float* x    = (const float*)d_in[0];
    const float* ln0s = (const float*)d_in[1];
    const float* ln0b = (const float*)d_in[2];
    const float* ln1s = (const float*)d_in[3];
    const float* ln1b = (const float*)d_in[4];
    const float* wq   = (const float*)d_in[5];
    const float* bq   = (const float*)d_in[6];
    const float* wk   = (const float*)d_in[7];
    const float* bk   = (const float*)d_in[8];
    const float* wv   = (const float*)d_in[9];
    const float* bv   = (const float*)d_in[10];
    const float* wo   = (const float*)d_in[11];
    const float* bo   = (const float*)d_in[12];
    const float* w0   = (const float*)d_in[13];
    const float* b0   = (const float*)d_in[14];
    const float* w1   = (const float*)d_in[15];
    const float* b1   = (const float*)d_in[16];
    float* out = (float*)d_out;

    // workspace layout (total = 128 MiB)
    char* p = (char*)d_ws;
    bf16* Wqkv = (bf16*)p; p += (size_t)3072 * 1024 * 2;
    bf16* Wot  = (bf16*)p; p += (size_t)1024 * 1024 * 2;
    bf16* W0t  = (bf16*)p; p += (size_t)4096 * 1024 * 2;
    bf16* W1t  = (bf16*)p; p += (size_t)1024 * 4096 * 2;
    bf16* y0   = (bf16*)p; p += (size_t)4096 * 1024 * 2;
    bf16* qbuf = (bf16*)p; p += (size_t)4096 * 1024 * 2;
    bf16* kbuf = (bf16*)p; p += (size_t)4096 * 1024 * 2;
    bf16* vbuf = (bf16*)p; p += (size_t)4096 * 1024 * 2;
    bf16* vtb  = (bf16*)p; p += (size_t)4096 * 1024 * 2;
    bf16* enc  = (bf16*)p; p += (size_t)4096 * 1024 * 2;
    float* x1  = (float*)p; p += (size_t)4096 * 1024 * 4;
    bf16* y1   = (bf16*)p; p += (size_t)4096 * 1024 * 2;
    bf16* h    = (bf16*)p; p += (size_t)4096 * 4096 * 2;

    const dim3 tb(32, 8);
    // weights -> bf16, transposed to [N][K]
    transpose_cast<<<dim3(32, 32), tb, 0, stream>>>(wq, Wqkv, 1024, 1024);
    transpose_cast<<<dim3(32, 32), tb, 0, stream>>>(wk, Wqkv + (size_t)1024 * 1024, 1024, 1024);
    transpose_cast<<<dim3(32, 32), tb, 0, stream>>>(wv, Wqkv + (size_t)2048 * 1024, 1024, 1024);
    transpose_cast<<<dim3(32, 32), tb, 0, stream>>>(wo, Wot, 1024, 1024);
    transpose_cast<<<dim3(128, 32), tb, 0, stream>>>(w0, W0t, 1024, 4096);
    transpose_cast<<<dim3(32, 128), tb, 0, stream>>>(w1, W1t, 4096, 1024);

    ln_kernel<<<4096, 256, 0, stream>>>(x, ln0s, ln0b, y0);

    // fused QKV projection: [4096,1024] @ [1024,3072]
    gemm_kernel<0><<<dim3(24, 32), 256, 0, stream>>>(
        y0, Wqkv, 4096, 3072, 1024, bq, bk, bv, nullptr, qbuf, kbuf, vbuf, nullptr);

    transpose_v<<<dim3(2, 64, 32), tb, 0, stream>>>(vbuf, vtb);

    attn_kernel<<<dim3(32, 32), 256, 0, stream>>>(qbuf, kbuf, vtb, enc);

    // out projection + residual -> x1 (fp32)
    gemm_kernel<1><<<dim3(8, 32), 256, 0, stream>>>(
        enc, Wot, 4096, 1024, 1024, bo, nullptr, nullptr, x, nullptr, nullptr, nullptr, x1);

    ln_kernel<<<4096, 256, 0, stream>>>(x1, ln1s, ln1b, y1);

    // MLP up + GELU -> h (bf16)
    gemm_kernel<2><<<dim3(32, 32), 256, 0, stream>>>(
        y1, W0t, 4096, 4096, 1024, b0, nullptr, nullptr, nullptr, h, nullptr, nullptr, nullptr);

    // MLP down + bias + residual -> out (fp32)
    gemm_kernel<1><<<dim3(8, 32), 256, 0, stream>>>(
        h, W1t, 4096, 1024, 4096, b1, nullptr, nullptr, x1, nullptr, nullptr, nullptr, out);
}

// Round 2
// 384.336 us; speedup vs baseline: 1.0108x; 1.0108x over previous
//
#include <hip/hip_runtime.h>
#include <cstdint>
#include <cstddef>

typedef __bf16 bf16;
typedef __attribute__((ext_vector_type(8))) __bf16 bf16x8;
typedef __attribute__((ext_vector_type(4))) __bf16 bf16x4;
typedef __attribute__((ext_vector_type(4))) float f32x4;

#define MFMA16 __builtin_amdgcn_mfma_f32_16x16x32_bf16

// async global -> LDS, 16B per lane. LDS dest is wave-uniform base + lane*16.
__device__ __forceinline__ void gload16(const bf16* g, bf16* l) {
    __builtin_amdgcn_global_load_lds(
        (const __attribute__((address_space(1))) uint32_t*)g,
        (__attribute__((address_space(3))) uint32_t*)l, 16, 0, 0);
}

// ---------------------------------------------------------------------------
// Tiled transpose + fp32->bf16 cast:  src [K][N] fp32  ->  dst [N][K] bf16
// ---------------------------------------------------------------------------
__global__ __launch_bounds__(256) void transpose_cast(
    const float* __restrict__ src, bf16* __restrict__ dst, int K, int N)
{
    __shared__ float t[32][33];
    const int n0 = blockIdx.x * 32, k0 = blockIdx.y * 32;
    const int tx = threadIdx.x, ty = threadIdx.y;
    #pragma unroll
    for (int i = ty; i < 32; i += 8)
        t[i][tx] = src[(size_t)(k0 + i) * N + n0 + tx];
    __syncthreads();
    #pragma unroll
    for (int i = ty; i < 32; i += 8)
        dst[(size_t)(n0 + i) * K + k0 + tx] = (bf16)t[tx][i];
}

// ---------------------------------------------------------------------------
// Batched bf16 transpose for V: src [Z][2048][64] -> dst [Z][64][2048]
// ---------------------------------------------------------------------------
__global__ __launch_bounds__(256) void transpose_v(
    const bf16* __restrict__ src, bf16* __restrict__ dst)
{
    __shared__ bf16 t[32][33];
    const int z = blockIdx.z;
    const int h0 = blockIdx.x * 32, s0 = blockIdx.y * 32;
    const bf16* sp = src + (size_t)z * 2048 * 64;
    bf16* dp = dst + (size_t)z * 64 * 2048;
    const int tx = threadIdx.x, ty = threadIdx.y;
    #pragma unroll
    for (int i = ty; i < 32; i += 8)
        t[i][tx] = sp[(size_t)(s0 + i) * 64 + h0 + tx];
    __syncthreads();
    #pragma unroll
    for (int i = ty; i < 32; i += 8)
        dp[(size_t)(h0 + i) * 2048 + s0 + tx] = t[tx][i];
}

// ---------------------------------------------------------------------------
// LayerNorm (D=1024) fp32 in -> bf16 out. One block (256 thr) per row.
// ---------------------------------------------------------------------------
__global__ __launch_bounds__(256) void ln_kernel(
    const float* __restrict__ x, const float* __restrict__ sc,
    const float* __restrict__ bi, bf16* __restrict__ y)
{
    const int row = blockIdx.x, tid = threadIdx.x;
    const f32x4 v = ((const f32x4*)(x + (size_t)row * 1024))[tid];
    float s  = v[0] + v[1] + v[2] + v[3];
    float s2 = v[0]*v[0] + v[1]*v[1] + v[2]*v[2] + v[3]*v[3];
    #pragma unroll
    for (int d = 1; d < 64; d <<= 1) {
        s  += __shfl_xor(s, d);
        s2 += __shfl_xor(s2, d);
    }
    __shared__ float red[8];
    if ((tid & 63) == 0) { red[tid >> 6] = s; red[4 + (tid >> 6)] = s2; }
    __syncthreads();
    s  = red[0] + red[1] + red[2] + red[3];
    s2 = red[4] + red[5] + red[6] + red[7];
    const float mu = s * (1.f / 1024.f);
    const float rstd = rsqrtf(s2 * (1.f / 1024.f) - mu * mu + 1e-6f);
    const f32x4 s4 = ((const f32x4*)sc)[tid];
    const f32x4 b4 = ((const f32x4*)bi)[tid];
    bf16x4 o;
    #pragma unroll
    for (int j = 0; j < 4; ++j)
        o[j] = (bf16)((v[j] - mu) * rstd * s4[j] + b4[j]);
    ((bf16x4*)(y + (size_t)row * 1024))[tid] = o;
}

// ---------------------------------------------------------------------------
// bf16 GEMM (m97 structure): C[M][N] = A[M][K] @ Bt[N][K]^T
// 128x128 tile, BK=32, 256 thr = 4 waves (2x2), 4x4 16x16x32 frags/wave.
// Staging via global_load_lds width=16 into LINEAR (unpadded) LDS.
// EPI 0: QKV scatter (+bias; Q pre-scaled by H^-0.5), bf16 out [B*N][T][H] x3
// EPI 1: fp32 out = acc + bias[col] + res[row][col]
// EPI 2: bf16 out = gelu_tanh(acc + bias[col])
// ---------------------------------------------------------------------------
template <int EPI>
__global__ __launch_bounds__(256) void gemm_kernel(
    const bf16* __restrict__ A, const bf16* __restrict__ Bt,
    int M, int N, int K,
    const float* __restrict__ b0, const float* __restrict__ b1,
    const float* __restrict__ b2, const float* __restrict__ res,
    bf16* __restrict__ o0, bf16* __restrict__ o1, bf16* __restrict__ o2,
    float* __restrict__ of)
{
    __shared__ bf16 As[128][32];   // linear: global_load_lds dest
    __shared__ bf16 Bs[128][32];

    const int tid = threadIdx.x;
    const int wave = tid >> 6, lane = tid & 63;
    const int wr = (wave >> 1) * 64, wc = (wave & 1) * 64;
    const int lr = lane & 15, lk = (lane >> 4) * 8;
    const int bm = blockIdx.y * 128, bn = blockIdx.x * 128;

    f32x4 acc[4][4] = {};

    // wave w stages rows [w*32, w*32+32) of both tiles as 2 chunks of 16 rows
    // chunk: lane l -> row base + (l>>2), elem col (l&3)*8  == dest base + l*16B
    const int srow = wave * 32 + (lane >> 2);
    const int scol = (lane & 3) * 8;
    const bf16* Ag = A  + (size_t)(bm + srow) * K + scol;
    const bf16* Bg = Bt + (size_t)(bn + srow) * K + scol;
    bf16* AsB = &As[wave * 32][0];
    bf16* BsB = &Bs[wave * 32][0];

    for (int k0 = 0; k0 < K; k0 += 32) {
        gload16(Ag + k0,                AsB);
        gload16(Ag + (size_t)16 * K + k0, AsB + 16 * 32);
        gload16(Bg + k0,                BsB);
        gload16(Bg + (size_t)16 * K + k0, BsB + 16 * 32);
        __syncthreads();
        bf16x8 a[4], b[4];
        #pragma unroll
        for (int m = 0; m < 4; ++m) a[m] = *(const bf16x8*)&As[wr + m * 16 + lr][lk];
        #pragma unroll
        for (int n = 0; n < 4; ++n) b[n] = *(const bf16x8*)&Bs[wc + n * 16 + lr][lk];
        #pragma unroll
        for (int m = 0; m < 4; ++m)
            #pragma unroll
            for (int n = 0; n < 4; ++n)
                acc[m][n] = MFMA16(a[m], b[n], acc[m][n], 0, 0, 0);
        __syncthreads();
    }

    const int rbase = bm + wr + ((lane >> 4) << 2);
    const int cbase = bn + wc + lr;
    #pragma unroll
    for (int m = 0; m < 4; ++m) {
        #pragma unroll
        for (int n = 0; n < 4; ++n) {
            const f32x4 v = acc[m][n];
            #pragma unroll
            for (int r = 0; r < 4; ++r) {
                const int row = rbase + m * 16 + r;
                const int col = cbase + n * 16;
                const float val = v[r];
                if constexpr (EPI == 0) {
                    const int which = col >> 10, cc = col & 1023;
                    const float* bp = (which == 0) ? b0 : (which == 1) ? b1 : b2;
                    bf16* dp = (which == 0) ? o0 : (which == 1) ? o1 : o2;
                    const float scl = (which == 0) ? 0.125f : 1.0f;  // H^-0.5 folded into Q
                    const int bb = row >> 11, t = row & 2047;
                    const int nh = cc >> 6, hh = cc & 63;
                    dp[(((size_t)(bb * 16 + nh) * 2048 + t) << 6) + hh] =
                        (bf16)((val + bp[cc]) * scl);
                } else if constexpr (EPI == 1) {
                    of[(size_t)row * N + col] =
                        val + b0[col] + res[(size_t)row * N + col];
                } else {
                    const float xg = val + b0[col];
                    const float g = 0.5f * xg *
                        (1.f + tanhf(0.7978845608f * (xg + 0.044715f * xg * xg * xg)));
                    o0[(size_t)row * N + col] = (bf16)g;
                }
            }
        }
    }
}

// ---------------------------------------------------------------------------
// Flash attention. Grid: (qt=T/64, z=B*N). 256 thr = 4 waves; each wave owns
// 16 Q rows. K tile [64 s][64 h], Vt tile [64 h][64 s] staged in LDS with
// async-STAGE split: next tile's global loads issued BEFORE compute, LDS
// write after the post-compute barrier (T14). Q pre-scaled by H^-0.5.
// q,k: [Z][T][H] bf16; vt: [Z][H][T] bf16; enc out: [B][T][N*H] bf16.
// ---------------------------------------------------------------------------
__global__ __launch_bounds__(256) void attn_kernel(
    const bf16* __restrict__ q, const bf16* __restrict__ k,
    const bf16* __restrict__ vt, bf16* __restrict__ enc)
{
    __shared__ bf16 Qs[64][72];
    __shared__ bf16 Ks[64][72];
    __shared__ bf16 Vs[64][72];       // [h][s]
    __shared__ bf16 Ps[4][16][72];    // per-wave P tile

    const int tid = threadIdx.x, wave = tid >> 6, lane = tid & 63;
    const int lr = lane & 15, lk = (lane >> 4) * 8;
    const int qt = blockIdx.x, z = blockIdx.y;
    const bf16* qb = q + ((size_t)z * 2048 + qt * 64) * 64;
    const bf16* kb = k + (size_t)z * 2048 * 64;
    const bf16* vb = vt + (size_t)z * 64 * 2048;

    const int sr = tid >> 3, so = (tid & 7) * 8;  // staging: rows sr, sr+32

    for (int c = tid; c < 512; c += 256) {
        const int r = c >> 3, o = (c & 7) * 8;
        *(bf16x8*)&Qs[r][o] = *(const bf16x8*)&qb[r * 64 + o];
    }

    bf16x8 kr0, kr1, vr0, vr1;
    auto load_tile = [&](int st) {
        kr0 = *(const bf16x8*)&kb[(size_t)(st * 64 + sr) * 64 + so];
        kr1 = *(const bf16x8*)&kb[(size_t)(st * 64 + sr + 32) * 64 + so];
        vr0 = *(const bf16x8*)&vb[(size_t)sr * 2048 + st * 64 + so];
        vr1 = *(const bf16x8*)&vb[(size_t)(sr + 32) * 2048 + st * 64 + so];
    };
    auto write_tile = [&]() {
        *(bf16x8*)&Ks[sr][so]      = kr0;
        *(bf16x8*)&Ks[sr + 32][so] = kr1;
        *(bf16x8*)&Vs[sr][so]      = vr0;
        *(bf16x8*)&Vs[sr + 32][so] = vr1;
    };

    load_tile(0);
    write_tile();
    __syncthreads();
    bf16x8 aq0 = *(const bf16x8*)&Qs[wave * 16 + lr][lk];
    bf16x8 aq1 = *(const bf16x8*)&Qs[wave * 16 + lr][32 + lk];

    float m_run[4] = {-1e30f, -1e30f, -1e30f, -1e30f};
    float l_run[4] = {0.f, 0.f, 0.f, 0.f};
    f32x4 accO[4] = {};

    for (int st = 0; st < 32; ++st) {
        if (st < 31) load_tile(st + 1);   // prefetch overlaps compute below

        f32x4 sa[4] = {};
        #pragma unroll
        for (int j = 0; j < 4; ++j) {
            sa[j] = MFMA16(aq0, *(const bf16x8*)&Ks[j * 16 + lr][lk], sa[j], 0, 0, 0);
            sa[j] = MFMA16(aq1, *(const bf16x8*)&Ks[j * 16 + lr][32 + lk], sa[j], 0, 0, 0);
        }

        float pm[4];
        #pragma unroll
        for (int r = 0; r < 4; ++r)
            pm[r] = fmaxf(fmaxf(sa[0][r], sa[1][r]), fmaxf(sa[2][r], sa[3][r]));
        #pragma unroll
        for (int d = 1; d < 16; d <<= 1)
            #pragma unroll
            for (int r = 0; r < 4; ++r) pm[r] = fmaxf(pm[r], __shfl_xor(pm[r], d));

        float fac[4], rs[4];
        #pragma unroll
        for (int r = 0; r < 4; ++r) {
            const float mn = fmaxf(m_run[r], pm[r]);
            fac[r] = __expf(m_run[r] - mn);
            m_run[r] = mn;
            rs[r] = 0.f;
        }
        #pragma unroll
        for (int j = 0; j < 4; ++j)
            #pragma unroll
            for (int r = 0; r < 4; ++r) {
                const float p = __expf(sa[j][r] - m_run[r]);
                sa[j][r] = p;
                rs[r] += p;
            }
        #pragma unroll
        for (int d = 1; d < 16; d <<= 1)
            #pragma unroll
            for (int r = 0; r < 4; ++r) rs[r] += __shfl_xor(rs[r], d);
        #pragma unroll
        for (int r = 0; r < 4; ++r) l_run[r] = l_run[r] * fac[r] + rs[r];

        #pragma unroll
        for (int nh = 0; nh < 4; ++nh)
            #pragma unroll
            for (int r = 0; r < 4; ++r) accO[nh][r] *= fac[r];

        #pragma unroll
        for (int j = 0; j < 4; ++j)
            #pragma unroll
            for (int r = 0; r < 4; ++r)
                Ps[wave][((lane >> 4) << 2) + r][j * 16 + lr] = (bf16)sa[j][r];

        #pragma unroll
        for (int nh = 0; nh < 4; ++nh) {
            accO[nh] = MFMA16(*(const bf16x8*)&Ps[wave][lr][lk],
                              *(const bf16x8*)&Vs[nh * 16 + lr][lk], accO[nh], 0, 0, 0);
            accO[nh] = MFMA16(*(const bf16x8*)&Ps[wave][lr][32 + lk],
                              *(const bf16x8*)&Vs[nh * 16 + lr][32 + lk], accO[nh], 0, 0, 0);
        }

        __syncthreads();                 // all waves done reading Ks/Vs
        if (st < 31) write_tile();       // land prefetched tile
        __syncthreads();
    }

    const int bb = z >> 4, nn = z & 15;
    #pragma unroll
    for (int nh = 0; nh < 4; ++nh)
        #pragma unroll
        for (int r = 0; r < 4; ++r) {
            const int t = qt * 64 + wave * 16 + ((lane >> 4) << 2) + r;
            const int hh = nh * 16 + lr;
            enc[((size_t)(bb * 2048 + t)) * 1024 + nn * 64 + hh] =
                (bf16)(accO[nh][r] / l_run[r]);
        }
}

// ---------------------------------------------------------------------------
extern "C" void kernel_launch(void* const* d_in, const int* in_sizes, int n_in,
                              void* d_out, int out_size, void* d_ws, size_t ws_size,
                              hipStream_t stream) {
    const float* x    = (const float*)d_in[0];
    const float* ln0s = (const float*)d_in[1];
    const float* ln0b = (const float*)d_in[2];
    const float* ln1s = (const float*)d_in[3];
    const float* ln1b = (const float*)d_in[4];
    const float* wq   = (const float*)d_in[5];
    const float* bq   = (const float*)d_in[6];
    const float* wk   = (const float*)d_in[7];
    const float* bk   = (const float*)d_in[8];
    const float* wv   = (const float*)d_in[9];
    const float* bv   = (const float*)d_in[10];
    const float* wo   = (const float*)d_in[11];
    const float* bo   = (const float*)d_in[12];
    const float* w0   = (const float*)d_in[13];
    const float* b0   = (const float*)d_in[14];
    const float* w1   = (const float*)d_in[15];
    const float* b1   = (const float*)d_in[16];
    float* out = (float*)d_out;

    // workspace layout (total = 128 MiB)
    char* p = (char*)d_ws;
    bf16* Wqkv = (bf16*)p; p += (size_t)3072 * 1024 * 2;
    bf16* Wot  = (bf16*)p; p += (size_t)1024 * 1024 * 2;
    bf16* W0t  = (bf16*)p; p += (size_t)4096 * 1024 * 2;
    bf16* W1t  = (bf16*)p; p += (size_t)1024 * 4096 * 2;
    bf16* y0   = (bf16*)p; p += (size_t)4096 * 1024 * 2;
    bf16* qbuf = (bf16*)p; p += (size_t)4096 * 1024 * 2;
    bf16* kbuf = (bf16*)p; p += (size_t)4096 * 1024 * 2;
    bf16* vbuf = (bf16*)p; p += (size_t)4096 * 1024 * 2;
    bf16* vtb  = (bf16*)p; p += (size_t)4096 * 1024 * 2;
    bf16* enc  = (bf16*)p; p += (size_t)4096 * 1024 * 2;
    float* x1  = (float*)p; p += (size_t)4096 * 1024 * 4;
    bf16* y1   = (bf16*)p; p += (size_t)4096 * 1024 * 2;
    bf16* h    = (bf16*)p; p += (size_t)4096 * 4096 * 2;

    const dim3 tb(32, 8);
    // weights -> bf16, transposed to [N][K]
    transpose_cast<<<dim3(32, 32), tb, 0, stream>>>(wq, Wqkv, 1024, 1024);
    transpose_cast<<<dim3(32, 32), tb, 0, stream>>>(wk, Wqkv + (size_t)1024 * 1024, 1024, 1024);
    transpose_cast<<<dim3(32, 32), tb, 0, stream>>>(wv, Wqkv + (size_t)2048 * 1024, 1024, 1024);
    transpose_cast<<<dim3(32, 32), tb, 0, stream>>>(wo, Wot, 1024, 1024);
    transpose_cast<<<dim3(128, 32), tb, 0, stream>>>(w0, W0t, 1024, 4096);
    transpose_cast<<<dim3(32, 128), tb, 0, stream>>>(w1, W1t, 4096, 1024);

    ln_kernel<<<4096, 256, 0, stream>>>(x, ln0s, ln0b, y0);

    // fused QKV projection: [4096,1024] @ [1024,3072]
    gemm_kernel<0><<<dim3(24, 32), 256, 0, stream>>>(
        y0, Wqkv, 4096, 3072, 1024, bq, bk, bv, nullptr, qbuf, kbuf, vbuf, nullptr);

    transpose_v<<<dim3(2, 64, 32), tb, 0, stream>>>(vbuf, vtb);

    attn_kernel<<<dim3(32, 32), 256, 0, stream>>>(qbuf, kbuf, vtb, enc);

    // out projection + residual -> x1 (fp32)
    gemm_kernel<1><<<dim3(8, 32), 256, 0, stream>>>(
        enc, Wot, 4096, 1024, 1024, bo, nullptr, nullptr, x, nullptr, nullptr, nullptr, x1);

    ln_kernel<<<4096, 256, 0, stream>>>(x1, ln1s, ln1b, y1);

    // MLP up + GELU -> h (bf16)
    gemm_kernel<2><<<dim3(32, 32), 256, 0, stream>>>(
        y1, W0t, 4096, 4096, 1024, b0, nullptr, nullptr, nullptr, h, nullptr, nullptr, nullptr);

    // MLP down + bias + residual -> out (fp32)
    gemm_kernel<1><<<dim3(8, 32), 256, 0, stream>>>(
        h, W1t, 4096, 1024, 4096, b1, nullptr, nullptr, x1, nullptr, nullptr, nullptr, out);
}

// Round 3
// 336.211 us; speedup vs baseline: 1.1555x; 1.1431x over previous
//
#include <hip/hip_runtime.h>
#include <cstdint>
#include <cstddef>

typedef __bf16 bf16;
typedef __attribute__((ext_vector_type(8))) __bf16 bf16x8;
typedef __attribute__((ext_vector_type(4))) __bf16 bf16x4;
typedef __attribute__((ext_vector_type(4))) float f32x4;

#define MFMA16 __builtin_amdgcn_mfma_f32_16x16x32_bf16

// async global -> LDS, 16B per lane. LDS dest is wave-uniform base + lane*16.
__device__ __forceinline__ void gload16(const bf16* g, bf16* l) {
    __builtin_amdgcn_global_load_lds(
        (const __attribute__((address_space(1))) uint32_t*)g,
        (__attribute__((address_space(3))) uint32_t*)l, 16, 0, 0);
}

// pack two f32 -> u32 of 2 bf16 (elem0 = lo bits); compiler emits cvt_pk
__device__ __forceinline__ unsigned pk2(float lo, float hi) {
    union { bf16 h[2]; unsigned u; } c;
    c.h[0] = (bf16)lo; c.h[1] = (bf16)hi;
    return c.u;
}
// v_permlane32_swap_b32: a' = [a.lo | b.lo], b' = [a.hi | b.hi]
__device__ __forceinline__ void pl32swap(unsigned& a, unsigned& b) {
    asm volatile("v_permlane32_swap_b32 %0, %1" : "+v"(a), "+v"(b));
}

// ---------------------------------------------------------------------------
// Tiled transpose + fp32->bf16 cast:  src [K][N] fp32  ->  dst [N][K] bf16
// ---------------------------------------------------------------------------
__global__ __launch_bounds__(256) void transpose_cast(
    const float* __restrict__ src, bf16* __restrict__ dst, int K, int N)
{
    __shared__ float t[32][33];
    const int n0 = blockIdx.x * 32, k0 = blockIdx.y * 32;
    const int tx = threadIdx.x, ty = threadIdx.y;
    #pragma unroll
    for (int i = ty; i < 32; i += 8)
        t[i][tx] = src[(size_t)(k0 + i) * N + n0 + tx];
    __syncthreads();
    #pragma unroll
    for (int i = ty; i < 32; i += 8)
        dst[(size_t)(n0 + i) * K + k0 + tx] = (bf16)t[tx][i];
}

// ---------------------------------------------------------------------------
// Batched bf16 transpose for V: src [Z][2048][64] -> dst [Z][64][2048]
// ---------------------------------------------------------------------------
__global__ __launch_bounds__(256) void transpose_v(
    const bf16* __restrict__ src, bf16* __restrict__ dst)
{
    __shared__ bf16 t[32][33];
    const int z = blockIdx.z;
    const int h0 = blockIdx.x * 32, s0 = blockIdx.y * 32;
    const bf16* sp = src + (size_t)z * 2048 * 64;
    bf16* dp = dst + (size_t)z * 64 * 2048;
    const int tx = threadIdx.x, ty = threadIdx.y;
    #pragma unroll
    for (int i = ty; i < 32; i += 8)
        t[i][tx] = sp[(size_t)(s0 + i) * 64 + h0 + tx];
    __syncthreads();
    #pragma unroll
    for (int i = ty; i < 32; i += 8)
        dp[(size_t)(h0 + i) * 2048 + s0 + tx] = t[tx][i];
}

// ---------------------------------------------------------------------------
// LayerNorm (D=1024) fp32 in -> bf16 out. One block (256 thr) per row.
// ---------------------------------------------------------------------------
__global__ __launch_bounds__(256) void ln_kernel(
    const float* __restrict__ x, const float* __restrict__ sc,
    const float* __restrict__ bi, bf16* __restrict__ y)
{
    const int row = blockIdx.x, tid = threadIdx.x;
    const f32x4 v = ((const f32x4*)(x + (size_t)row * 1024))[tid];
    float s  = v[0] + v[1] + v[2] + v[3];
    float s2 = v[0]*v[0] + v[1]*v[1] + v[2]*v[2] + v[3]*v[3];
    #pragma unroll
    for (int d = 1; d < 64; d <<= 1) {
        s  += __shfl_xor(s, d);
        s2 += __shfl_xor(s2, d);
    }
    __shared__ float red[8];
    if ((tid & 63) == 0) { red[tid >> 6] = s; red[4 + (tid >> 6)] = s2; }
    __syncthreads();
    s  = red[0] + red[1] + red[2] + red[3];
    s2 = red[4] + red[5] + red[6] + red[7];
    const float mu = s * (1.f / 1024.f);
    const float rstd = rsqrtf(s2 * (1.f / 1024.f) - mu * mu + 1e-6f);
    const f32x4 s4 = ((const f32x4*)sc)[tid];
    const f32x4 b4 = ((const f32x4*)bi)[tid];
    bf16x4 o;
    #pragma unroll
    for (int j = 0; j < 4; ++j)
        o[j] = (bf16)((v[j] - mu) * rstd * s4[j] + b4[j]);
    ((bf16x4*)(y + (size_t)row * 1024))[tid] = o;
}

// ---------------------------------------------------------------------------
// bf16 GEMM: C[M][N] = A[M][K] @ Bt[N][K]^T, tile 128 x BN (BN=128 or 64).
// BK=32, 256 thr = 4 waves (2x2). global_load_lds width=16, linear LDS.
// EPI 0: QKV scatter (+bias; Q pre-scaled by H^-0.5), bf16 out [B*N][T][H] x3
// EPI 1: fp32 out = acc + bias[col] + res[row][col]
// EPI 2: bf16 out = gelu_tanh(acc + bias[col])
// ---------------------------------------------------------------------------
template <int EPI, int BN>
__global__ __launch_bounds__(256) void gemm_kernel(
    const bf16* __restrict__ A, const bf16* __restrict__ Bt,
    int M, int N, int K,
    const float* __restrict__ b0, const float* __restrict__ b1,
    const float* __restrict__ b2, const float* __restrict__ res,
    bf16* __restrict__ o0, bf16* __restrict__ o1, bf16* __restrict__ o2,
    float* __restrict__ of)
{
    constexpr int NF = BN / 32;      // col frags per wave (4 or 2)
    __shared__ bf16 As[128][32];
    __shared__ bf16 Bs[BN][32];

    const int tid = threadIdx.x;
    const int wave = tid >> 6, lane = tid & 63;
    const int wr = (wave >> 1) * 64, wc = (wave & 1) * (BN / 2);
    const int lr = lane & 15, lk = (lane >> 4) * 8;
    const int bm = blockIdx.y * 128, bn = blockIdx.x * BN;

    f32x4 acc[4][NF] = {};

    const int srow = wave * 32 + (lane >> 2);
    const int scol = (lane & 3) * 8;
    const bf16* Ag = A  + (size_t)(bm + srow) * K + scol;
    const bf16* Bg = Bt + (size_t)(bn + srow) * K + scol;
    bf16* AsB = &As[wave * 32][0];
    bf16* BsB = &Bs[(wave * 32) % BN][0];

    for (int k0 = 0; k0 < K; k0 += 32) {
        gload16(Ag + k0,                  AsB);
        gload16(Ag + (size_t)16 * K + k0, AsB + 16 * 32);
        if constexpr (BN == 128) {
            gload16(Bg + k0,                  BsB);
            gload16(Bg + (size_t)16 * K + k0, BsB + 16 * 32);
        } else {
            if (wave < 2) {
                gload16(Bg + k0,                  BsB);
                gload16(Bg + (size_t)16 * K + k0, BsB + 16 * 32);
            }
        }
        __syncthreads();
        bf16x8 a[4], b[NF];
        #pragma unroll
        for (int m = 0; m < 4; ++m) a[m] = *(const bf16x8*)&As[wr + m * 16 + lr][lk];
        #pragma unroll
        for (int n = 0; n < NF; ++n) b[n] = *(const bf16x8*)&Bs[wc + n * 16 + lr][lk];
        #pragma unroll
        for (int m = 0; m < 4; ++m)
            #pragma unroll
            for (int n = 0; n < NF; ++n)
                acc[m][n] = MFMA16(a[m], b[n], acc[m][n], 0, 0, 0);
        __syncthreads();
    }

    const int rbase = bm + wr + ((lane >> 4) << 2);
    const int cbase = bn + wc + lr;
    #pragma unroll
    for (int m = 0; m < 4; ++m) {
        #pragma unroll
        for (int n = 0; n < NF; ++n) {
            const f32x4 v = acc[m][n];
            #pragma unroll
            for (int r = 0; r < 4; ++r) {
                const int row = rbase + m * 16 + r;
                const int col = cbase + n * 16;
                const float val = v[r];
                if constexpr (EPI == 0) {
                    const int which = col >> 10, cc = col & 1023;
                    const float* bp = (which == 0) ? b0 : (which == 1) ? b1 : b2;
                    bf16* dp = (which == 0) ? o0 : (which == 1) ? o1 : o2;
                    const float scl = (which == 0) ? 0.125f : 1.0f;  // H^-0.5 in Q
                    const int bb = row >> 11, t = row & 2047;
                    const int nh = cc >> 6, hh = cc & 63;
                    dp[(((size_t)(bb * 16 + nh) * 2048 + t) << 6) + hh] =
                        (bf16)((val + bp[cc]) * scl);
                } else if constexpr (EPI == 1) {
                    of[(size_t)row * N + col] =
                        val + b0[col] + res[(size_t)row * N + col];
                } else {
                    const float xg = val + b0[col];
                    const float g = 0.5f * xg *
                        (1.f + tanhf(0.7978845608f * (xg + 0.044715f * xg * xg * xg)));
                    o0[(size_t)row * N + col] = (bf16)g;
                }
            }
        }
    }
}

// ---------------------------------------------------------------------------
// Flash attention, swapped-QK^T + in-register softmax.
// Grid: (qt=T/64, z=B*N). 256 thr = 4 waves; wave owns 16 q rows.
// QK^T computed as mfma(K_frag, Q_frag) -> lane holds full P row for
// q = lane&15 (16 s values at s = j*16 + (lane>>4)*4 + r). Softmax is
// in-lane + 2 shuffles. P -> PV A-frag via cvt_pk + permlane32_swap +
// shfl_xor(16). Defer-max (THR=8). Q pre-scaled by H^-0.5.
// ---------------------------------------------------------------------------
__global__ __launch_bounds__(256) void attn_kernel(
    const bf16* __restrict__ q, const bf16* __restrict__ k,
    const bf16* __restrict__ vt, bf16* __restrict__ enc)
{
    __shared__ bf16 Qs[64][72];
    __shared__ bf16 Ks[64][72];
    __shared__ bf16 Vs[64][72];       // [h][s]

    const int tid = threadIdx.x, wave = tid >> 6, lane = tid & 63;
    const int lr = lane & 15, lk = (lane >> 4) * 8;
    const bool geven = ((lane >> 4) & 1) == 0;
    const int qsel = (lane >> 4) << 2;         // accO row base (q' = qsel + r)
    const int qt = blockIdx.x, z = blockIdx.y;
    const bf16* qb = q + ((size_t)z * 2048 + qt * 64) * 64;
    const bf16* kb = k + (size_t)z * 2048 * 64;
    const bf16* vb = vt + (size_t)z * 64 * 2048;

    const int sr = tid >> 3, so = (tid & 7) * 8;

    for (int c = tid; c < 512; c += 256) {
        const int r = c >> 3, o = (c & 7) * 8;
        *(bf16x8*)&Qs[r][o] = *(const bf16x8*)&qb[r * 64 + o];
    }

    bf16x8 kr0, kr1, vr0, vr1;
    auto load_tile = [&](int st) {
        kr0 = *(const bf16x8*)&kb[(size_t)(st * 64 + sr) * 64 + so];
        kr1 = *(const bf16x8*)&kb[(size_t)(st * 64 + sr + 32) * 64 + so];
        vr0 = *(const bf16x8*)&vb[(size_t)sr * 2048 + st * 64 + so];
        vr1 = *(const bf16x8*)&vb[(size_t)(sr + 32) * 2048 + st * 64 + so];
    };
    auto write_tile = [&]() {
        *(bf16x8*)&Ks[sr][so]      = kr0;
        *(bf16x8*)&Ks[sr + 32][so] = kr1;
        *(bf16x8*)&Vs[sr][so]      = vr0;
        *(bf16x8*)&Vs[sr + 32][so] = vr1;
    };

    load_tile(0);
    write_tile();
    __syncthreads();
    const bf16x8 aq0 = *(const bf16x8*)&Qs[wave * 16 + lr][lk];
    const bf16x8 aq1 = *(const bf16x8*)&Qs[wave * 16 + lr][32 + lk];

    float m_run = -1e30f, l_run = 0.f;
    f32x4 accO[4] = {};

    for (int kt = 0; kt < 32; ++kt) {
        if (kt < 31) load_tile(kt + 1);   // prefetch into regs

        // QK^T swapped: p4[j][r] = S[q=lane&15][s = j*16 + (lane>>4)*4 + r]
        f32x4 p4[4] = {};
        __builtin_amdgcn_s_setprio(1);
        #pragma unroll
        for (int j = 0; j < 4; ++j) {
            p4[j] = MFMA16(*(const bf16x8*)&Ks[j * 16 + lr][lk],      aq0, p4[j], 0, 0, 0);
            p4[j] = MFMA16(*(const bf16x8*)&Ks[j * 16 + lr][32 + lk], aq1, p4[j], 0, 0, 0);
        }
        __builtin_amdgcn_s_setprio(0);

        // row max (per q): in-lane over 16 + 2 cross-group shuffles
        float pmax = p4[0][0];
        #pragma unroll
        for (int j = 0; j < 4; ++j)
            #pragma unroll
            for (int r = 0; r < 4; ++r) pmax = fmaxf(pmax, p4[j][r]);
        pmax = fmaxf(pmax, __shfl_xor(pmax, 16));
        pmax = fmaxf(pmax, __shfl_xor(pmax, 32));

        // defer-max: rescale only when max grew by > 8
        if (__any(pmax - m_run > 8.0f)) {
            const float mnew = fmaxf(m_run, pmax);
            const float fac = __expf(m_run - mnew);
            m_run = mnew;
            l_run *= fac;
            float facq[4];
            #pragma unroll
            for (int r = 0; r < 4; ++r) facq[r] = __shfl(fac, qsel + r);
            #pragma unroll
            for (int nh = 0; nh < 4; ++nh)
                #pragma unroll
                for (int r = 0; r < 4; ++r) accO[nh][r] *= facq[r];
        }

        float rsum = 0.f;
        #pragma unroll
        for (int j = 0; j < 4; ++j)
            #pragma unroll
            for (int r = 0; r < 4; ++r) {
                const float e = __expf(p4[j][r] - m_run);
                p4[j][r] = e;
                rsum += e;
            }
        rsum += __shfl_xor(rsum, 16);
        rsum += __shfl_xor(rsum, 32);
        l_run += rsum;

        // pack pairs along s: w[j][rr] = bf16x2(s=j*16+g*4+2rr, +1)
        unsigned w[4][2];
        #pragma unroll
        for (int j = 0; j < 4; ++j) {
            w[j][0] = pk2(p4[j][0], p4[j][1]);
            w[j][1] = pk2(p4[j][2], p4[j][3]);
        }
        // build PV A-frags: lane needs P[q][s = f*32 + g*8 + i], i=0..7
        union FW { unsigned u[4]; bf16x8 v; } f0, f1;
        #pragma unroll
        for (int f = 0; f < 2; ++f) {
            FW& fw = f ? f1 : f0;
            #pragma unroll
            for (int rr = 0; rr < 2; ++rr) {
                unsigned X = w[2 * f][rr], Y = w[2 * f + 1][rr];
                pl32swap(X, Y);                       // X=[Xlo|Ylo], Y=[Xhi|Yhi]
                const unsigned SX = (unsigned)__shfl_xor((int)X, 16);
                const unsigned SY = (unsigned)__shfl_xor((int)Y, 16);
                fw.u[rr]     = geven ? X  : SY;       // words t=0,1 (first src)
                fw.u[2 + rr] = geven ? SX : Y;        // words t=2,3 (second src)
            }
        }

        __builtin_amdgcn_s_setprio(1);
        #pragma unroll
        for (int nh = 0; nh < 4; ++nh) {
            accO[nh] = MFMA16(f0.v, *(const bf16x8*)&Vs[nh * 16 + lr][lk],      accO[nh], 0, 0, 0);
            accO[nh] = MFMA16(f1.v, *(const bf16x8*)&Vs[nh * 16 + lr][32 + lk], accO[nh], 0, 0, 0);
        }
        __builtin_amdgcn_s_setprio(0);

        __syncthreads();
        if (kt < 31) write_tile();
        __syncthreads();
    }

    float lq[4];
    #pragma unroll
    for (int r = 0; r < 4; ++r) lq[r] = __shfl(l_run, qsel + r);

    const int bb = z >> 4, nn = z & 15;
    #pragma unroll
    for (int nh = 0; nh < 4; ++nh)
        #pragma unroll
        for (int r = 0; r < 4; ++r) {
            const int t = qt * 64 + wave * 16 + qsel + r;
            const int hh = nh * 16 + lr;
            enc[((size_t)(bb * 2048 + t)) * 1024 + nn * 64 + hh] =
                (bf16)(accO[nh][r] / lq[r]);
        }
}

// ---------------------------------------------------------------------------
extern "C" void kernel_launch(void* const* d_in, const int* in_sizes, int n_in,
                              void* d_out, int out_size, void* d_ws, size_t ws_size,
                              hipStream_t stream) {
    const float* x    = (const float*)d_in[0];
    const float* ln0s = (const float*)d_in[1];
    const float* ln0b = (const float*)d_in[2];
    const float* ln1s = (const float*)d_in[3];
    const float* ln1b = (const float*)d_in[4];
    const float* wq   = (const float*)d_in[5];
    const float* bq   = (const float*)d_in[6];
    const float* wk   = (const float*)d_in[7];
    const float* bk   = (const float*)d_in[8];
    const float* wv   = (const float*)d_in[9];
    const float* bv   = (const float*)d_in[10];
    const float* wo   = (const float*)d_in[11];
    const float* bo   = (const float*)d_in[12];
    const float* w0   = (const float*)d_in[13];
    const float* b0   = (const float*)d_in[14];
    const float* w1   = (const float*)d_in[15];
    const float* b1   = (const float*)d_in[16];
    float* out = (float*)d_out;

    // workspace layout (total = 128 MiB)
    char* p = (char*)d_ws;
    bf16* Wqkv = (bf16*)p; p += (size_t)3072 * 1024 * 2;
    bf16* Wot  = (bf16*)p; p += (size_t)1024 * 1024 * 2;
    bf16* W0t  = (bf16*)p; p += (size_t)4096 * 1024 * 2;
    bf16* W1t  = (bf16*)p; p += (size_t)1024 * 4096 * 2;
    bf16* y0   = (bf16*)p; p += (size_t)4096 * 1024 * 2;
    bf16* qbuf = (bf16*)p; p += (size_t)4096 * 1024 * 2;
    bf16* kbuf = (bf16*)p; p += (size_t)4096 * 1024 * 2;
    bf16* vbuf = (bf16*)p; p += (size_t)4096 * 1024 * 2;
    bf16* vtb  = (bf16*)p; p += (size_t)4096 * 1024 * 2;
    bf16* enc  = (bf16*)p; p += (size_t)4096 * 1024 * 2;
    float* x1  = (float*)p; p += (size_t)4096 * 1024 * 4;
    bf16* y1   = (bf16*)p; p += (size_t)4096 * 1024 * 2;
    bf16* h    = (bf16*)p; p += (size_t)4096 * 4096 * 2;

    const dim3 tb(32, 8);
    // weights -> bf16, transposed to [N][K]
    transpose_cast<<<dim3(32, 32), tb, 0, stream>>>(wq, Wqkv, 1024, 1024);
    transpose_cast<<<dim3(32, 32), tb, 0, stream>>>(wk, Wqkv + (size_t)1024 * 1024, 1024, 1024);
    transpose_cast<<<dim3(32, 32), tb, 0, stream>>>(wv, Wqkv + (size_t)2048 * 1024, 1024, 1024);
    transpose_cast<<<dim3(32, 32), tb, 0, stream>>>(wo, Wot, 1024, 1024);
    transpose_cast<<<dim3(128, 32), tb, 0, stream>>>(w0, W0t, 1024, 4096);
    transpose_cast<<<dim3(32, 128), tb, 0, stream>>>(w1, W1t, 4096, 1024);

    ln_kernel<<<4096, 256, 0, stream>>>(x, ln0s, ln0b, y0);

    // fused QKV projection: [4096,1024] @ [1024,3072]
    gemm_kernel<0, 128><<<dim3(24, 32), 256, 0, stream>>>(
        y0, Wqkv, 4096, 3072, 1024, bq, bk, bv, nullptr, qbuf, kbuf, vbuf, nullptr);

    transpose_v<<<dim3(2, 64, 32), tb, 0, stream>>>(vbuf, vtb);

    attn_kernel<<<dim3(32, 32), 256, 0, stream>>>(qbuf, kbuf, vtb, enc);

    // out projection + residual -> x1 (fp32); BN=64 -> 512 wg (2/CU)
    gemm_kernel<1, 64><<<dim3(16, 32), 256, 0, stream>>>(
        enc, Wot, 4096, 1024, 1024, bo, nullptr, nullptr, x, nullptr, nullptr, nullptr, x1);

    ln_kernel<<<4096, 256, 0, stream>>>(x1, ln1s, ln1b, y1);

    // MLP up + GELU -> h (bf16)
    gemm_kernel<2, 128><<<dim3(32, 32), 256, 0, stream>>>(
        y1, W0t, 4096, 4096, 1024, b0, nullptr, nullptr, nullptr, h, nullptr, nullptr, nullptr);

    // MLP down + bias + residual -> out (fp32); BN=64 -> 512 wg (2/CU)
    gemm_kernel<1, 64><<<dim3(16, 32), 256, 0, stream>>>(
        h, W1t, 4096, 1024, 4096, b1, nullptr, nullptr, x1, nullptr, nullptr, nullptr, out);
}

// Round 4
// 298.645 us; speedup vs baseline: 1.3008x; 1.1258x over previous
//
#include <hip/hip_runtime.h>
#include <cstdint>
#include <cstddef>

typedef __bf16 bf16;
typedef __attribute__((ext_vector_type(8))) __bf16 bf16x8;
typedef __attribute__((ext_vector_type(4))) __bf16 bf16x4;
typedef __attribute__((ext_vector_type(4))) float f32x4;

#define MFMA16 __builtin_amdgcn_mfma_f32_16x16x32_bf16

// async global -> LDS, 16B per lane. LDS dest is wave-uniform base + lane*16.
__device__ __forceinline__ void gload16(const bf16* g, bf16* l) {
    __builtin_amdgcn_global_load_lds(
        (const __attribute__((address_space(1))) uint32_t*)g,
        (__attribute__((address_space(3))) uint32_t*)l, 16, 0, 0);
}

// pack two f32 -> u32 of 2 bf16 (elem0 = lo bits); compiler emits cvt_pk
__device__ __forceinline__ unsigned pk2(float lo, float hi) {
    union { bf16 h[2]; unsigned u; } c;
    c.h[0] = (bf16)lo; c.h[1] = (bf16)hi;
    return c.u;
}
// v_permlane32_swap_b32: a' = [a.lo | b.lo], b' = [a.hi | b.hi]
__device__ __forceinline__ void pl32swap(unsigned& a, unsigned& b) {
    asm volatile("v_permlane32_swap_b32 %0, %1" : "+v"(a), "+v"(b));
}

// bijective XCD chunk swizzle (nwg % 8 == 0): XCD x gets tiles [x*nwg/8, ...)
__device__ __forceinline__ int xcd_swz(int id, int nwg) {
    return (id & 7) * (nwg >> 3) + (id >> 3);
}

// ---------------------------------------------------------------------------
// Tiled transpose + fp32->bf16 cast:  src [K][N] fp32  ->  dst [N][K] bf16
// ---------------------------------------------------------------------------
__global__ __launch_bounds__(256) void transpose_cast(
    const float* __restrict__ src, bf16* __restrict__ dst, int K, int N)
{
    __shared__ float t[32][33];
    const int n0 = blockIdx.x * 32, k0 = blockIdx.y * 32;
    const int tx = threadIdx.x, ty = threadIdx.y;
    #pragma unroll
    for (int i = ty; i < 32; i += 8)
        t[i][tx] = src[(size_t)(k0 + i) * N + n0 + tx];
    __syncthreads();
    #pragma unroll
    for (int i = ty; i < 32; i += 8)
        dst[(size_t)(n0 + i) * K + k0 + tx] = (bf16)t[tx][i];
}

// ---------------------------------------------------------------------------
// Batched bf16 transpose for V: src [Z][2048][64] -> dst [Z][64][2048]
// ---------------------------------------------------------------------------
__global__ __launch_bounds__(256) void transpose_v(
    const bf16* __restrict__ src, bf16* __restrict__ dst)
{
    __shared__ bf16 t[32][33];
    const int z = blockIdx.z;
    const int h0 = blockIdx.x * 32, s0 = blockIdx.y * 32;
    const bf16* sp = src + (size_t)z * 2048 * 64;
    bf16* dp = dst + (size_t)z * 64 * 2048;
    const int tx = threadIdx.x, ty = threadIdx.y;
    #pragma unroll
    for (int i = ty; i < 32; i += 8)
        t[i][tx] = sp[(size_t)(s0 + i) * 64 + h0 + tx];
    __syncthreads();
    #pragma unroll
    for (int i = ty; i < 32; i += 8)
        dp[(size_t)(h0 + i) * 2048 + s0 + tx] = t[tx][i];
}

// ---------------------------------------------------------------------------
// LayerNorm (D=1024) fp32 in -> bf16 out. One block (256 thr) per row.
// ---------------------------------------------------------------------------
__global__ __launch_bounds__(256) void ln_kernel(
    const float* __restrict__ x, const float* __restrict__ sc,
    const float* __restrict__ bi, bf16* __restrict__ y)
{
    const int row = blockIdx.x, tid = threadIdx.x;
    const f32x4 v = ((const f32x4*)(x + (size_t)row * 1024))[tid];
    float s  = v[0] + v[1] + v[2] + v[3];
    float s2 = v[0]*v[0] + v[1]*v[1] + v[2]*v[2] + v[3]*v[3];
    #pragma unroll
    for (int d = 1; d < 64; d <<= 1) {
        s  += __shfl_xor(s, d);
        s2 += __shfl_xor(s2, d);
    }
    __shared__ float red[8];
    if ((tid & 63) == 0) { red[tid >> 6] = s; red[4 + (tid >> 6)] = s2; }
    __syncthreads();
    s  = red[0] + red[1] + red[2] + red[3];
    s2 = red[4] + red[5] + red[6] + red[7];
    const float mu = s * (1.f / 1024.f);
    const float rstd = rsqrtf(s2 * (1.f / 1024.f) - mu * mu + 1e-6f);
    const f32x4 s4 = ((const f32x4*)sc)[tid];
    const f32x4 b4 = ((const f32x4*)bi)[tid];
    bf16x4 o;
    #pragma unroll
    for (int j = 0; j < 4; ++j)
        o[j] = (bf16)((v[j] - mu) * rstd * s4[j] + b4[j]);
    ((bf16x4*)(y + (size_t)row * 1024))[tid] = o;
}

// ---------------------------------------------------------------------------
// bf16 GEMM, LDS double-buffered (2-phase): C[M][N] = A[M][K] @ Bt[N][K]^T.
// Tile 128 x BN, BK=32, 256 thr = 4 waves (2x2). Per K-step: issue next
// tile's global_load_lds FIRST, then ds_read+MFMA current, then ONE
// __syncthreads (its vmcnt(0) lands the prefetch that flew under compute).
// EPI 0: QKV scatter (+bias; Q pre-scaled by H^-0.5), bf16 out [B*N][T][H] x3
// EPI 1: fp32 out = acc + bias[col] + res[row][col]
// EPI 2: bf16 out = gelu(acc + bias[col])   (sigmoid-form, __expf)
// ---------------------------------------------------------------------------
template <int EPI, int BN>
__global__ __launch_bounds__(256) void gemm_kernel(
    const bf16* __restrict__ A, const bf16* __restrict__ Bt,
    int M, int N, int K,
    const float* __restrict__ b0, const float* __restrict__ b1,
    const float* __restrict__ b2, const float* __restrict__ res,
    bf16* __restrict__ o0, bf16* __restrict__ o1, bf16* __restrict__ o2,
    float* __restrict__ of)
{
    constexpr int NF = BN / 32;      // col frags per wave (4 or 2)
    __shared__ bf16 As[2][128][32];
    __shared__ bf16 Bs[2][BN][32];

    const int tid = threadIdx.x;
    const int wave = tid >> 6, lane = tid & 63;
    const int wr = (wave >> 1) * 64, wc = (wave & 1) * (BN / 2);
    const int lr = lane & 15, lk = (lane >> 4) * 8;

    const int nwg = gridDim.x * gridDim.y;
    const int id = xcd_swz(blockIdx.y * gridDim.x + blockIdx.x, nwg);
    const int bm = (id / gridDim.x) * 128, bn = (id % gridDim.x) * BN;

    f32x4 acc[4][NF] = {};

    const int srow = wave * 32 + (lane >> 2);
    const int scol = (lane & 3) * 8;
    const bf16* Ag = A  + (size_t)(bm + srow) * K + scol;
    const bf16* Bg = Bt + (size_t)(bn + srow) * K + scol;

    auto stage = [&](int buf, int k0) {
        bf16* AsB = &As[buf][wave * 32][0];
        gload16(Ag + k0,                  AsB);
        gload16(Ag + (size_t)16 * K + k0, AsB + 16 * 32);
        if constexpr (BN == 128) {
            bf16* BsB = &Bs[buf][wave * 32][0];
            gload16(Bg + k0,                  BsB);
            gload16(Bg + (size_t)16 * K + k0, BsB + 16 * 32);
        } else {
            if (wave < 2) {
                bf16* BsB = &Bs[buf][wave * 32][0];
                gload16(Bg + k0,                  BsB);
                gload16(Bg + (size_t)16 * K + k0, BsB + 16 * 32);
            }
        }
    };

    const int nk = K >> 5;
    stage(0, 0);
    __syncthreads();
    int cur = 0;
    for (int i = 0; i < nk; ++i) {
        if (i + 1 < nk) stage(cur ^ 1, (i + 1) << 5);   // prefetch flies under MFMA
        bf16x8 a[4], b[NF];
        #pragma unroll
        for (int m = 0; m < 4; ++m) a[m] = *(const bf16x8*)&As[cur][wr + m * 16 + lr][lk];
        #pragma unroll
        for (int n = 0; n < NF; ++n) b[n] = *(const bf16x8*)&Bs[cur][wc + n * 16 + lr][lk];
        #pragma unroll
        for (int m = 0; m < 4; ++m)
            #pragma unroll
            for (int n = 0; n < NF; ++n)
                acc[m][n] = MFMA16(a[m], b[n], acc[m][n], 0, 0, 0);
        __syncthreads();   // implicit vmcnt(0): prefetch landed; cur is free
        cur ^= 1;
    }

    const int rbase = bm + wr + ((lane >> 4) << 2);
    const int cbase = bn + wc + lr;
    #pragma unroll
    for (int m = 0; m < 4; ++m) {
        #pragma unroll
        for (int n = 0; n < NF; ++n) {
            const f32x4 v = acc[m][n];
            #pragma unroll
            for (int r = 0; r < 4; ++r) {
                const int row = rbase + m * 16 + r;
                const int col = cbase + n * 16;
                const float val = v[r];
                if constexpr (EPI == 0) {
                    const int which = col >> 10, cc = col & 1023;
                    const float* bp = (which == 0) ? b0 : (which == 1) ? b1 : b2;
                    bf16* dp = (which == 0) ? o0 : (which == 1) ? o1 : o2;
                    const float scl = (which == 0) ? 0.125f : 1.0f;  // H^-0.5 in Q
                    const int bb = row >> 11, t = row & 2047;
                    const int nh = cc >> 6, hh = cc & 63;
                    dp[(((size_t)(bb * 16 + nh) * 2048 + t) << 6) + hh] =
                        (bf16)((val + bp[cc]) * scl);
                } else if constexpr (EPI == 1) {
                    of[(size_t)row * N + col] =
                        val + b0[col] + res[(size_t)row * N + col];
                } else {
                    const float xg = val + b0[col];
                    const float z2 = 1.5957691216f * (xg + 0.044715f * xg * xg * xg);
                    o0[(size_t)row * N + col] = (bf16)(xg / (1.f + __expf(-z2)));
                }
            }
        }
    }
}

// ---------------------------------------------------------------------------
// Flash attention, swapped-QK^T + in-register softmax (unchanged from R3
// except XCD swizzle). Grid: T/64 x B*N. 4 waves; wave owns 16 q rows.
// ---------------------------------------------------------------------------
__global__ __launch_bounds__(256) void attn_kernel(
    const bf16* __restrict__ q, const bf16* __restrict__ k,
    const bf16* __restrict__ vt, bf16* __restrict__ enc)
{
    __shared__ bf16 Qs[64][72];
    __shared__ bf16 Ks[64][72];
    __shared__ bf16 Vs[64][72];       // [h][s]

    const int tid = threadIdx.x, wave = tid >> 6, lane = tid & 63;
    const int lr = lane & 15, lk = (lane >> 4) * 8;
    const bool geven = ((lane >> 4) & 1) == 0;
    const int qsel = (lane >> 4) << 2;
    const int id = xcd_swz(blockIdx.y * gridDim.x + blockIdx.x, 1024);
    const int qt = id % 32, z = id / 32;
    const bf16* qb = q + ((size_t)z * 2048 + qt * 64) * 64;
    const bf16* kb = k + (size_t)z * 2048 * 64;
    const bf16* vb = vt + (size_t)z * 64 * 2048;

    const int sr = tid >> 3, so = (tid & 7) * 8;

    for (int c = tid; c < 512; c += 256) {
        const int r = c >> 3, o = (c & 7) * 8;
        *(bf16x8*)&Qs[r][o] = *(const bf16x8*)&qb[r * 64 + o];
    }

    bf16x8 kr0, kr1, vr0, vr1;
    auto load_tile = [&](int st) {
        kr0 = *(const bf16x8*)&kb[(size_t)(st * 64 + sr) * 64 + so];
        kr1 = *(const bf16x8*)&kb[(size_t)(st * 64 + sr + 32) * 64 + so];
        vr0 = *(const bf16x8*)&vb[(size_t)sr * 2048 + st * 64 + so];
        vr1 = *(const bf16x8*)&vb[(size_t)(sr + 32) * 2048 + st * 64 + so];
    };
    auto write_tile = [&]() {
        *(bf16x8*)&Ks[sr][so]      = kr0;
        *(bf16x8*)&Ks[sr + 32][so] = kr1;
        *(bf16x8*)&Vs[sr][so]      = vr0;
        *(bf16x8*)&Vs[sr + 32][so] = vr1;
    };

    load_tile(0);
    write_tile();
    __syncthreads();
    const bf16x8 aq0 = *(const bf16x8*)&Qs[wave * 16 + lr][lk];
    const bf16x8 aq1 = *(const bf16x8*)&Qs[wave * 16 + lr][32 + lk];

    float m_run = -1e30f, l_run = 0.f;
    f32x4 accO[4] = {};

    for (int kt = 0; kt < 32; ++kt) {
        if (kt < 31) load_tile(kt + 1);   // reg prefetch

        f32x4 p4[4] = {};
        __builtin_amdgcn_s_setprio(1);
        #pragma unroll
        for (int j = 0; j < 4; ++j) {
            p4[j] = MFMA16(*(const bf16x8*)&Ks[j * 16 + lr][lk],      aq0, p4[j], 0, 0, 0);
            p4[j] = MFMA16(*(const bf16x8*)&Ks[j * 16 + lr][32 + lk], aq1, p4[j], 0, 0, 0);
        }
        __builtin_amdgcn_s_setprio(0);

        float pmax = p4[0][0];
        #pragma unroll
        for (int j = 0; j < 4; ++j)
            #pragma unroll
            for (int r = 0; r < 4; ++r) pmax = fmaxf(pmax, p4[j][r]);
        pmax = fmaxf(pmax, __shfl_xor(pmax, 16));
        pmax = fmaxf(pmax, __shfl_xor(pmax, 32));

        if (__any(pmax - m_run > 8.0f)) {
            const float mnew = fmaxf(m_run, pmax);
            const float fac = __expf(m_run - mnew);
            m_run = mnew;
            l_run *= fac;
            float facq[4];
            #pragma unroll
            for (int r = 0; r < 4; ++r) facq[r] = __shfl(fac, qsel + r);
            #pragma unroll
            for (int nh = 0; nh < 4; ++nh)
                #pragma unroll
                for (int r = 0; r < 4; ++r) accO[nh][r] *= facq[r];
        }

        float rsum = 0.f;
        #pragma unroll
        for (int j = 0; j < 4; ++j)
            #pragma unroll
            for (int r = 0; r < 4; ++r) {
                const float e = __expf(p4[j][r] - m_run);
                p4[j][r] = e;
                rsum += e;
            }
        rsum += __shfl_xor(rsum, 16);
        rsum += __shfl_xor(rsum, 32);
        l_run += rsum;

        unsigned w[4][2];
        #pragma unroll
        for (int j = 0; j < 4; ++j) {
            w[j][0] = pk2(p4[j][0], p4[j][1]);
            w[j][1] = pk2(p4[j][2], p4[j][3]);
        }
        union FW { unsigned u[4]; bf16x8 v; } f0, f1;
        #pragma unroll
        for (int f = 0; f < 2; ++f) {
            FW& fw = f ? f1 : f0;
            #pragma unroll
            for (int rr = 0; rr < 2; ++rr) {
                unsigned X = w[2 * f][rr], Y = w[2 * f + 1][rr];
                pl32swap(X, Y);
                const unsigned SX = (unsigned)__shfl_xor((int)X, 16);
                const unsigned SY = (unsigned)__shfl_xor((int)Y, 16);
                fw.u[rr]     = geven ? X  : SY;
                fw.u[2 + rr] = geven ? SX : Y;
            }
        }

        __builtin_amdgcn_s_setprio(1);
        #pragma unroll
        for (int nh = 0; nh < 4; ++nh) {
            accO[nh] = MFMA16(f0.v, *(const bf16x8*)&Vs[nh * 16 + lr][lk],      accO[nh], 0, 0, 0);
            accO[nh] = MFMA16(f1.v, *(const bf16x8*)&Vs[nh * 16 + lr][32 + lk], accO[nh], 0, 0, 0);
        }
        __builtin_amdgcn_s_setprio(0);

        __syncthreads();
        if (kt < 31) write_tile();
        __syncthreads();
    }

    float lq[4];
    #pragma unroll
    for (int r = 0; r < 4; ++r) lq[r] = __shfl(l_run, qsel + r);

    const int bb = z >> 4, nn = z & 15;
    #pragma unroll
    for (int nh = 0; nh < 4; ++nh)
        #pragma unroll
        for (int r = 0; r < 4; ++r) {
            const int t = qt * 64 + wave * 16 + qsel + r;
            const int hh = nh * 16 + lr;
            enc[((size_t)(bb * 2048 + t)) * 1024 + nn * 64 + hh] =
                (bf16)(accO[nh][r] / lq[r]);
        }
}

// ---------------------------------------------------------------------------
extern "C" void kernel_launch(void* const* d_in, const int* in_sizes, int n_in,
                              void* d_out, int out_size, void* d_ws, size_t ws_size,
                              hipStream_t stream) {
    const float* x    = (const float*)d_in[0];
    const float* ln0s = (const float*)d_in[1];
    const float* ln0b = (const float*)d_in[2];
    const float* ln1s = (const float*)d_in[3];
    const float* ln1b = (const float*)d_in[4];
    const float* wq   = (const float*)d_in[5];
    const float* bq   = (const float*)d_in[6];
    const float* wk   = (const float*)d_in[7];
    const float* bk   = (const float*)d_in[8];
    const float* wv   = (const float*)d_in[9];
    const float* bv   = (const float*)d_in[10];
    const float* wo   = (const float*)d_in[11];
    const float* bo   = (const float*)d_in[12];
    const float* w0   = (const float*)d_in[13];
    const float* b0   = (const float*)d_in[14];
    const float* w1   = (const float*)d_in[15];
    const float* b1   = (const float*)d_in[16];
    float* out = (float*)d_out;

    // workspace layout (total = 128 MiB)
    char* p = (char*)d_ws;
    bf16* Wqkv = (bf16*)p; p += (size_t)3072 * 1024 * 2;
    bf16* Wot  = (bf16*)p; p += (size_t)1024 * 1024 * 2;
    bf16* W0t  = (bf16*)p; p += (size_t)4096 * 1024 * 2;
    bf16* W1t  = (bf16*)p; p += (size_t)1024 * 4096 * 2;
    bf16* y0   = (bf16*)p; p += (size_t)4096 * 1024 * 2;
    bf16* qbuf = (bf16*)p; p += (size_t)4096 * 1024 * 2;
    bf16* kbuf = (bf16*)p; p += (size_t)4096 * 1024 * 2;
    bf16* vbuf = (bf16*)p; p += (size_t)4096 * 1024 * 2;
    bf16* vtb  = (bf16*)p; p += (size_t)4096 * 1024 * 2;
    bf16* enc  = (bf16*)p; p += (size_t)4096 * 1024 * 2;
    float* x1  = (float*)p; p += (size_t)4096 * 1024 * 4;
    bf16* y1   = (bf16*)p; p += (size_t)4096 * 1024 * 2;
    bf16* h    = (bf16*)p; p += (size_t)4096 * 4096 * 2;

    const dim3 tb(32, 8);
    // weights -> bf16, transposed to [N][K]
    transpose_cast<<<dim3(32, 32), tb, 0, stream>>>(wq, Wqkv, 1024, 1024);
    transpose_cast<<<dim3(32, 32), tb, 0, stream>>>(wk, Wqkv + (size_t)1024 * 1024, 1024, 1024);
    transpose_cast<<<dim3(32, 32), tb, 0, stream>>>(wv, Wqkv + (size_t)2048 * 1024, 1024, 1024);
    transpose_cast<<<dim3(32, 32), tb, 0, stream>>>(wo, Wot, 1024, 1024);
    transpose_cast<<<dim3(128, 32), tb, 0, stream>>>(w0, W0t, 1024, 4096);
    transpose_cast<<<dim3(32, 128), tb, 0, stream>>>(w1, W1t, 4096, 1024);

    ln_kernel<<<4096, 256, 0, stream>>>(x, ln0s, ln0b, y0);

    // fused QKV projection: [4096,1024] @ [1024,3072]
    gemm_kernel<0, 128><<<dim3(24, 32), 256, 0, stream>>>(
        y0, Wqkv, 4096, 3072, 1024, bq, bk, bv, nullptr, qbuf, kbuf, vbuf, nullptr);

    transpose_v<<<dim3(2, 64, 32), tb, 0, stream>>>(vbuf, vtb);

    attn_kernel<<<dim3(32, 32), 256, 0, stream>>>(qbuf, kbuf, vtb, enc);

    // out projection + residual -> x1 (fp32); BN=64 -> 512 wg
    gemm_kernel<1, 64><<<dim3(16, 32), 256, 0, stream>>>(
        enc, Wot, 4096, 1024, 1024, bo, nullptr, nullptr, x, nullptr, nullptr, nullptr, x1);

    ln_kernel<<<4096, 256, 0, stream>>>(x1, ln1s, ln1b, y1);

    // MLP up + GELU -> h (bf16)
    gemm_kernel<2, 128><<<dim3(32, 32), 256, 0, stream>>>(
        y1, W0t, 4096, 4096, 1024, b0, nullptr, nullptr, nullptr, h, nullptr, nullptr, nullptr);

    // MLP down + bias + residual -> out (fp32); BN=64 -> 512 wg
    gemm_kernel<1, 64><<<dim3(16, 32), 256, 0, stream>>>(
        h, W1t, 4096, 1024, 4096, b1, nullptr, nullptr, x1, nullptr, nullptr, nullptr, out);
}